// Round 1
// baseline (169.911 us; speedup 1.0000x reference)
//
#include <hip/hip_runtime.h>

// Problem constants (from reference): x shape (B, T, A, D) fp32
#define BB 256
#define TT 2048
#define AD 44          // A*D = 22*2
#define AD4 11         // float4 chunks per (b,t)
#define BLOCKS_PER_B 88  // T*AD4/256 = 2048*11/256

// Kernel 1: per-batch gap detection + endpoint row capture.
// NaN mask is identical across all 44 channels, so probe channel 0 only.
__global__ __launch_bounds__(256) void find_gap_kernel(
    const float* __restrict__ x,
    int* __restrict__ starts,
    int* __restrict__ ends,
    float* __restrict__ xs,
    float* __restrict__ xe) {
  const int b = blockIdx.x;
  const int tid = threadIdx.x;
  const float* row = x + (size_t)b * TT * AD;

  int lmin = TT;   // first NaN t
  int lmax = -1;   // last NaN t
  for (int t = tid; t < TT; t += 256) {
    float v = row[(size_t)t * AD];   // channel (a=0,d=0)
    if (v != v) {                    // isnan
      lmin = min(lmin, t);
      lmax = max(lmax, t);
    }
  }

  __shared__ int smin[256];
  __shared__ int smax[256];
  smin[tid] = lmin;
  smax[tid] = lmax;
  __syncthreads();
  for (int s = 128; s > 0; s >>= 1) {
    if (tid < s) {
      smin[tid] = min(smin[tid], smin[tid + s]);
      smax[tid] = max(smax[tid], smax[tid + s]);
    }
    __syncthreads();
  }

  __shared__ int s_start, s_end;
  if (tid == 0) {
    s_start = smin[0] - 1;  // index before first NaN
    s_end   = smax[0] + 1;  // index after last NaN
    starts[b] = s_start;
    ends[b]   = s_end;
  }
  __syncthreads();

  const int st = s_start;
  const int en = s_end;
  if (tid < AD) {
    xs[b * AD + tid] = row[(size_t)st * AD + tid];
    xe[b * AD + tid] = row[(size_t)en * AD + tid];
  }
}

// Kernel 2: streaming copy with in-gap linear interpolation. float4 lanes.
__global__ __launch_bounds__(256) void interp_kernel(
    const float4* __restrict__ x4,
    float4* __restrict__ out4,
    const int* __restrict__ starts,
    const int* __restrict__ ends,
    const float4* __restrict__ xs4,
    const float4* __restrict__ xe4) {
  const int b = blockIdx.x / BLOCKS_PER_B;           // block-uniform
  const int rem = (blockIdx.x % BLOCKS_PER_B) * 256 + threadIdx.x;
  const int t = rem / AD4;
  const int c4 = rem - t * AD4;
  const size_t idx = (size_t)b * (TT * AD4) + rem;

  float4 v = x4[idx];
  const int s = starts[b];
  const int e = ends[b];
  if (t > s && t < e) {
    const float w = (float)(t - s) / (float)(e - s);
    const float omw = 1.0f - w;
    const float4 a = xs4[b * AD4 + c4];
    const float4 z = xe4[b * AD4 + c4];
    v.x = a.x * omw + z.x * w;
    v.y = a.y * omw + z.y * w;
    v.z = a.z * omw + z.z * w;
    v.w = a.w * omw + z.w * w;
  }
  out4[idx] = v;
}

extern "C" void kernel_launch(void* const* d_in, const int* in_sizes, int n_in,
                              void* d_out, int out_size, void* d_ws, size_t ws_size,
                              hipStream_t stream) {
  const float* x = (const float*)d_in[0];
  float* out = (float*)d_out;

  // Workspace layout (all within first ~92 KB of d_ws):
  //   [0, 1KB)      : starts (256 int)
  //   [1KB, 2KB)    : ends   (256 int)
  //   [2KB, +45KB)  : xs (256*44 float)  -- x[b, start, :, :]
  //   [...,+45KB)   : xe (256*44 float)  -- x[b, end, :, :]
  char* ws = (char*)d_ws;
  int* starts = (int*)(ws);
  int* ends = (int*)(ws + 1024);
  float* xs = (float*)(ws + 2048);
  float* xe = (float*)(ws + 2048 + BB * AD * sizeof(float));

  find_gap_kernel<<<BB, 256, 0, stream>>>(x, starts, ends, xs, xe);

  interp_kernel<<<BB * BLOCKS_PER_B, 256, 0, stream>>>(
      (const float4*)x, (float4*)out, starts, ends,
      (const float4*)xs, (const float4*)xe);
}